// Round 1
// baseline (430.704 us; speedup 1.0000x reference)
//
#include <hip/hip_runtime.h>
#include <cmath>

#define NB 2
#define NT 32
#define NH 65
#define NW 65
#define NC 32
#define NF 32
#define NKS 15
#define NHP 33
#define NWP 33
#define NWR 33
#define NWOUT 64
#define PI_F 3.14159265358979323846f

// ---------------- Kernel A: conv3x3 stride2 SAME + bias + gelu -> partial stats
// block per (b,t,i): computes stats[b,t,i,j,f] for all (j,f), writes to partial[b][t*NHP+i][j*NF+f]
__global__ __launch_bounds__(256) void conv_stats_kernel(
    const float* __restrict__ x, const float* __restrict__ w,
    const float* __restrict__ bias, float* __restrict__ partial)
{
    __shared__ float rows[3 * NW * NC];   // 24.96 KB
    __shared__ float wsh[9 * NC * NF];    // 36.86 KB
    int blk = blockIdx.x;
    int b = blk / (NT * NHP);
    int r = blk % (NT * NHP);
    int t = r / NHP;
    int i = r % NHP;
    int tid = threadIdx.x;

    for (int idx = tid; idx < 9 * NC * NF; idx += 256) wsh[idx] = w[idx];

    const float* xbase = x + ((size_t)(b * NT + t) * NH) * (NW * NC);
    for (int idx = tid; idx < 3 * NW * NC; idx += 256) {
        int di = idx / (NW * NC);
        int rest = idx % (NW * NC);
        int row = 2 * i - 1 + di;
        float v = 0.f;
        if (row >= 0 && row < NH) v = xbase[(size_t)row * NW * NC + rest];
        rows[idx] = v;
    }
    __syncthreads();

    float* pout = partial + ((size_t)b * (NT * NHP) + (t * NHP + i)) * (NWP * NF);
    for (int idx = tid; idx < NWP * NF; idx += 256) {
        int j = idx / NF, f = idx % NF;
        float acc = bias[f];
        for (int dj = 0; dj < 3; ++dj) {
            int col = 2 * j - 1 + dj;
            if (col < 0 || col >= NW) continue;
            for (int di = 0; di < 3; ++di) {
                const float* rp = &rows[(di * NW + col) * NC];
                const float* wp = &wsh[(di * 3 + dj) * NC * NF + f];
                #pragma unroll
                for (int c = 0; c < NC; ++c)
                    acc = fmaf(rp[c], wp[c * NF], acc);
            }
        }
        // gelu (tanh approximation)
        float x3 = acc * acc * acc;
        float g = 0.5f * acc * (1.f + tanhf(0.7978845608028654f * (acc + 0.044715f * x3)));
        pout[idx] = g;
    }
}

// ---------------- Kernel A2: reduce partial over (t,i) -> ctx (B,NWP,NF), includes 1/(T*HP)
__global__ __launch_bounds__(256) void ctx_reduce_kernel(
    const float* __restrict__ partial, float* __restrict__ ctx)
{
    int idx = blockIdx.x * 256 + threadIdx.x;
    if (idx >= NB * NWP * NF) return;
    int jf = idx % (NWP * NF);
    int b = idx / (NWP * NF);
    const float* p = partial + (size_t)b * (NT * NHP) * (NWP * NF) + jf;
    float s = 0.f;
    for (int ti = 0; ti < NT * NHP; ++ti) s += p[(size_t)ti * (NWP * NF)];
    ctx[idx] = s * (1.f / (NT * NHP));
}

// ---------------- Kernel B: gates (sigmoid/sigmoid/softplus/softplus)
__global__ __launch_bounds__(256) void gate_kernel(
    const float* __restrict__ ctx,
    const float* __restrict__ wA, const float* __restrict__ bA,
    const float* __restrict__ wD, const float* __restrict__ bD,
    const float* __restrict__ wM, const float* __restrict__ bM,
    const float* __restrict__ wG, const float* __restrict__ bG,
    float* __restrict__ alpha, float* __restrict__ delta,
    float* __restrict__ mu, float* __restrict__ gamma)
{
    int idx = blockIdx.x * 256 + threadIdx.x;
    if (idx >= NB * NWP * NC) return;
    int c = idx % NC;
    int bw = idx / NC;
    float sA = bA[c], sD = bD[c], sM = bM[c], sG = bG[c];
    #pragma unroll
    for (int f = 0; f < NF; ++f) {
        float v = ctx[bw * NF + f];
        sA = fmaf(v, wA[f * NC + c], sA);
        sD = fmaf(v, wD[f * NC + c], sD);
        sM = fmaf(v, wM[f * NC + c], sM);
        sG = fmaf(v, wG[f * NC + c], sG);
    }
    alpha[idx] = 1.f / (1.f + expf(-sA));
    delta[idx] = 1.f / (1.f + expf(-sD));
    mu[idx]    = fmaxf(sM, 0.f) + log1pf(expf(-fabsf(sM)));
    gamma[idx] = fmaxf(sG, 0.f) + log1pf(expf(-fabsf(sG)));
}

// ---------------- Kernel C: kernel spectra K_E, K_I = rfft2(pad(k)) ; offset 25
__global__ __launch_bounds__(256) void spec_kernel(
    const float* __restrict__ kexc, const float* __restrict__ kinh,
    float2* __restrict__ KE, float2* __restrict__ KI)
{
    __shared__ float2 tw[NH];
    int tid = threadIdx.x;
    if (tid < NH) {
        float a = -2.f * PI_F * (float)tid / (float)NH;
        tw[tid] = make_float2(cosf(a), sinf(a));   // e^{-2pi i n / 65}
    }
    __syncthreads();
    int idx = blockIdx.x * 256 + tid;
    if (idx >= NH * NWR * NC) return;
    int c = idx % NC;
    int rem = idx / NC;
    int wr = rem % NWR;
    int h = rem / NWR;
    float ker = 0, kei = 0, kir = 0, kii = 0;
    int prow = (25 * (h + wr)) % NH;
    for (int i = 0; i < NKS; ++i) {
        int p = prow;
        for (int j = 0; j < NKS; ++j) {
            float2 e = tw[p];
            float ve = kexc[(i * NKS + j) * NC + c];
            float vi = kinh[(i * NKS + j) * NC + c];
            ker = fmaf(ve, e.x, ker); kei = fmaf(ve, e.y, kei);
            kir = fmaf(vi, e.x, kir); kii = fmaf(vi, e.y, kii);
            p += wr; if (p >= NH) p -= NH;
        }
        prow += h; if (prow >= NH) prow -= NH;
    }
    KE[idx] = make_float2(ker, kei);
    KI[idx] = make_float2(kir, kii);
}

// ---------------- Kernel D: real->complex DFT along W (65 -> 33). block per (b,t,h)
__global__ __launch_bounds__(256) void dft_rows_kernel(
    const float* __restrict__ x, float2* __restrict__ U1)
{
    __shared__ float row[NW * NC];   // 8.32 KB
    __shared__ float2 tw[NH];
    int tid = threadIdx.x;
    if (tid < NH) {
        float a = -2.f * PI_F * (float)tid / (float)NH;
        tw[tid] = make_float2(cosf(a), sinf(a));
    }
    int blk = blockIdx.x;  // (b*T+t)*H + h
    const float* xp = x + (size_t)blk * (NW * NC);
    for (int idx = tid; idx < NW * NC; idx += 256) row[idx] = xp[idx];
    __syncthreads();

    int c = tid & 31;
    int w0 = tid >> 5;   // 0..7
    float2 acc[5];
    int pidx[5];
    #pragma unroll
    for (int k = 0; k < 5; ++k) { acc[k] = make_float2(0.f, 0.f); pidx[k] = 0; }
    for (int q = 0; q < NW; ++q) {
        float v = row[q * NC + c];
        #pragma unroll
        for (int k = 0; k < 5; ++k) {
            int wr = w0 + 8 * k;
            if (wr < NWR) {
                float2 e = tw[pidx[k]];
                acc[k].x = fmaf(v, e.x, acc[k].x);
                acc[k].y = fmaf(v, e.y, acc[k].y);
                pidx[k] += wr; if (pidx[k] >= NH) pidx[k] -= NH;
            }
        }
    }
    float2* up = U1 + (size_t)blk * (NWR * NC);
    #pragma unroll
    for (int k = 0; k < 5; ++k) {
        int wr = w0 + 8 * k;
        if (wr < NWR) up[wr * NC + c] = acc[k];
    }
}

// ---------------- Kernel E/G: complex DFT along H (65 pt), in-place safe per block.
// SIGN=-1 forward, SIGN=+1 inverse; SCALE applies 1/65.
template <int SIGN, bool SCALE>
__global__ __launch_bounds__(256) void dft_cols_kernel(
    const float2* __restrict__ in, float2* __restrict__ out)
{
    __shared__ float2 col[NH * NC];   // 16.64 KB
    __shared__ float2 tw[NH];
    int tid = threadIdx.x;
    if (tid < NH) {
        float a = (float)SIGN * 2.f * PI_F * (float)tid / (float)NH;
        tw[tid] = make_float2(cosf(a), sinf(a));
    }
    int blk = blockIdx.x;   // (b*T+t)*NWR + wr
    int wr = blk % NWR;
    int bt = blk / NWR;
    const float2* ip = in + ((size_t)bt * NH) * (NWR * NC) + wr * NC;
    for (int idx = tid; idx < NH * NC; idx += 256) {
        int p = idx >> 5, c = idx & 31;
        col[idx] = ip[(size_t)p * (NWR * NC) + c];
    }
    __syncthreads();

    int c = tid & 31;
    int h0 = tid >> 5;   // 0..7
    float2 acc[9];
    int pidx[9];
    #pragma unroll
    for (int k = 0; k < 9; ++k) { acc[k] = make_float2(0.f, 0.f); pidx[k] = 0; }
    for (int p = 0; p < NH; ++p) {
        float2 v = col[p * NC + c];
        #pragma unroll
        for (int k = 0; k < 9; ++k) {
            int h = h0 + 8 * k;
            if (h < NH) {
                float2 e = tw[pidx[k]];
                acc[k].x = fmaf(v.x, e.x, fmaf(-v.y, e.y, acc[k].x));
                acc[k].y = fmaf(v.x, e.y, fmaf(v.y, e.x, acc[k].y));
                pidx[k] += h; if (pidx[k] >= NH) pidx[k] -= NH;
            }
        }
    }
    float2* op = out + ((size_t)bt * NH) * (NWR * NC) + wr * NC;
    const float s = SCALE ? (1.f / (float)NH) : 1.f;
    #pragma unroll
    for (int k = 0; k < 9; ++k) {
        int h = h0 + 8 * k;
        if (h < NH) op[(size_t)h * (NWR * NC) + c] = make_float2(acc[k].x * s, acc[k].y * s);
    }
}

// ---------------- Kernel F: SSM scan over T, in place (reads U_hat slot, writes Y slot)
__global__ __launch_bounds__(256) void scan_kernel(
    float2* __restrict__ buf, const float2* __restrict__ KE,
    const float2* __restrict__ KI, const float* __restrict__ alpha,
    const float* __restrict__ delta, const float* __restrict__ mu,
    const float* __restrict__ gamma)
{
    int idx = blockIdx.x * 256 + threadIdx.x;
    if (idx >= NB * NH * NWR * NC) return;
    int c = idx % NC;
    int rem = idx / NC;
    int wr = rem % NWR;
    int rem2 = rem / NWR;
    int h = rem2 % NH;
    int b = rem2 / NH;

    int gi = (b * NWP + wr) * NC + c;
    float axx = 0.9f * alpha[gi];
    float ayy = 0.9f * delta[gi];
    float m = mu[gi], g = gamma[gi];
    float2 ki = KI[(h * NWR + wr) * NC + c];
    float2 ke = KE[(h * NWR + wr) * NC + c];
    float2 axy = make_float2(-ki.x * m, -ki.y * m);
    float2 ayx = make_float2(ke.x * g, ke.y * g);

    float2 xs = make_float2(0.f, 0.f), ys = make_float2(0.f, 0.f);
    size_t base = ((size_t)b * NT) * NH * NWR * NC + (size_t)h * (NWR * NC) + wr * NC + c;
    const size_t stride = (size_t)NH * NWR * NC;
    for (int t = 0; t < NT; ++t) {
        float2 U = buf[base + (size_t)t * stride];
        float2 nx, ny;
        nx.x = fmaf(axx, xs.x, fmaf(axy.x, ys.x, fmaf(-axy.y, ys.y, U.x)));
        nx.y = fmaf(axx, xs.y, fmaf(axy.x, ys.y, fmaf(axy.y, ys.x, U.y)));
        ny.x = fmaf(ayx.x, xs.x, fmaf(-ayx.y, xs.y, ayy * ys.x));
        ny.y = fmaf(ayx.x, xs.y, fmaf(ayx.y, xs.x, ayy * ys.y));
        xs = nx; ys = ny;
        buf[base + (size_t)t * stride] = ys;
    }
}

// ---------------- Kernel H: irfft along W (33 complex -> 64 real), 1/64; DC+Nyquist imag ignored
__global__ __launch_bounds__(256) void irfft_w_kernel(
    const float2* __restrict__ Z, float* __restrict__ out)
{
    __shared__ float2 z[NWR * NC];   // 8.45 KB
    __shared__ float2 tw[NWOUT];
    int tid = threadIdx.x;
    if (tid < NWOUT) {
        float a = 2.f * PI_F * (float)tid / (float)NWOUT;
        tw[tid] = make_float2(cosf(a), sinf(a));   // e^{+2pi i n/64}
    }
    int blk = blockIdx.x;   // (b*T+t)*H + h
    const float2* zp = Z + (size_t)blk * (NWR * NC);
    for (int idx = tid; idx < NWR * NC; idx += 256) z[idx] = zp[idx];
    __syncthreads();

    int c = tid & 31;
    int w0 = tid >> 5;
    float acc[8];
    int pidx[8];
    float z0 = z[0 * NC + c].x;
    float zn = z[32 * NC + c].x;
    #pragma unroll
    for (int k = 0; k < 8; ++k) {
        int ow = w0 + 8 * k;
        acc[k] = z0 + ((ow & 1) ? -zn : zn);
        pidx[k] = 0;
    }
    for (int q = 1; q < 32; ++q) {
        float2 v = z[q * NC + c];
        #pragma unroll
        for (int k = 0; k < 8; ++k) {
            int ow = w0 + 8 * k;
            pidx[k] += ow; pidx[k] &= 63;
            float2 e = tw[pidx[k]];
            acc[k] = fmaf(2.f * v.x, e.x, fmaf(-2.f * v.y, e.y, acc[k]));
        }
    }
    float* op = out + (size_t)blk * (NWOUT * NC);
    #pragma unroll
    for (int k = 0; k < 8; ++k) {
        int ow = w0 + 8 * k;
        op[ow * NC + c] = acc[k] * (1.f / (float)NWOUT);
    }
}

extern "C" void kernel_launch(void* const* d_in, const int* in_sizes, int n_in,
                              void* d_out, int out_size, void* d_ws, size_t ws_size,
                              hipStream_t stream)
{
    const float* x     = (const float*)d_in[0];
    const float* convw = (const float*)d_in[1];
    const float* convb = (const float*)d_in[2];
    const float* wA = (const float*)d_in[3];
    const float* bA = (const float*)d_in[4];
    const float* wD = (const float*)d_in[5];
    const float* bD = (const float*)d_in[6];
    const float* wM = (const float*)d_in[7];
    const float* bM = (const float*)d_in[8];
    const float* wG = (const float*)d_in[9];
    const float* bG = (const float*)d_in[10];
    const float* kexc = (const float*)d_in[11];
    const float* kinh = (const float*)d_in[12];

    const size_t NBIG = (size_t)NB * NT * NH * NWR * NC;   // 4,392,960 complex
    char* ws = (char*)d_ws;
    float2* bufA    = (float2*)ws;  ws += NBIG * sizeof(float2);                    // 35.1 MB
    float2* KE      = (float2*)ws;  ws += (size_t)NH * NWR * NC * sizeof(float2);   // 1.1 MB
    float2* KI      = (float2*)ws;  ws += (size_t)NH * NWR * NC * sizeof(float2);   // 1.1 MB
    float*  partial = (float*)ws;   ws += (size_t)NB * (NT * NHP) * (NWP * NF) * sizeof(float); // 8.9 MB
    float*  ctx     = (float*)ws;   ws += (size_t)NB * NWP * NF * sizeof(float);
    float*  alpha   = (float*)ws;   ws += (size_t)NB * NWP * NC * sizeof(float);
    float*  delta   = (float*)ws;   ws += (size_t)NB * NWP * NC * sizeof(float);
    float*  mu      = (float*)ws;   ws += (size_t)NB * NWP * NC * sizeof(float);
    float*  gamma   = (float*)ws;   ws += (size_t)NB * NWP * NC * sizeof(float);

    // context branch
    conv_stats_kernel<<<NB * NT * NHP, 256, 0, stream>>>(x, convw, convb, partial);
    ctx_reduce_kernel<<<(NB * NWP * NF + 255) / 256, 256, 0, stream>>>(partial, ctx);
    gate_kernel<<<(NB * NWP * NC + 255) / 256, 256, 0, stream>>>(
        ctx, wA, bA, wD, bD, wM, bM, wG, bG, alpha, delta, mu, gamma);

    // kernel spectra
    spec_kernel<<<(NH * NWR * NC + 255) / 256, 256, 0, stream>>>(kexc, kinh, KE, KI);

    // forward rfft2 of input: rows then cols (in place for cols)
    dft_rows_kernel<<<NB * NT * NH, 256, 0, stream>>>(x, bufA);
    dft_cols_kernel<-1, false><<<NB * NT * NWR, 256, 0, stream>>>(bufA, bufA);

    // SSM scan over T (in place: U_hat -> Y)
    scan_kernel<<<(NB * NH * NWR * NC + 255) / 256, 256, 0, stream>>>(
        bufA, KE, KI, alpha, delta, mu, gamma);

    // inverse: ifft along H (1/65), then irfft along W (1/64) into d_out
    dft_cols_kernel<+1, true><<<NB * NT * NWR, 256, 0, stream>>>(bufA, bufA);
    irfft_w_kernel<<<NB * NT * NH, 256, 0, stream>>>(bufA, (float*)d_out);
}